// Round 4
// baseline (927.039 us; speedup 1.0000x reference)
//
#include <hip/hip_runtime.h>

#define NF 128
#define NB_AGG 40
#define QCAP 512

// ---------- power iteration (blocks 0,1) + edge packing (blocks >=2) ----------
// block 0: inv_sigma[0], writes W1t[k][j] = W1[j][k]*inv_sigma[0], zeroes colsum/colsumsq
// block 1: inv_sigma[1]
// blocks >=2: pk[e] = (dst[e]<<16) | src[e]
__global__ __launch_bounds__(512) void power_pack_kernel(
    const float* __restrict__ W1, const float* __restrict__ u1,
    const float* __restrict__ W2, const float* __restrict__ u2,
    const int* __restrict__ ei, unsigned int* __restrict__ pk, int n_edges,
    float* __restrict__ inv_sigma, float* __restrict__ W1t,
    float* __restrict__ colzero) {
    __shared__ float Wl[128][129];
    __shared__ float us[128], vv[128], part[4][128], red[128];
    int tid = threadIdx.x;

    if (blockIdx.x >= 2) {
        int idx = (blockIdx.x - 2) * 512 + tid;
        int stride = (gridDim.x - 2) * 512;
        const int* srcs = ei;
        const int* dsts = ei + n_edges;
        for (int e = idx; e < n_edges; e += stride)
            pk[e] = ((unsigned)dsts[e] << 16) | (unsigned)srcs[e];
        return;
    }

    const float* W = blockIdx.x ? W2 : W1;
    const float* u = blockIdx.x ? u2 : u1;
    const float4* W4 = (const float4*)W;
    for (int j = tid; j < 4096; j += 512) {
        float4 w = W4[j];
        int r = j >> 5, c0 = (j & 31) << 2;
        Wl[r][c0] = w.x; Wl[r][c0 + 1] = w.y; Wl[r][c0 + 2] = w.z; Wl[r][c0 + 3] = w.w;
    }
    if (tid < 128) us[tid] = u[tid];
    if (blockIdx.x == 0 && tid >= 256 && tid < 512) colzero[tid - 256] = 0.f;
    __syncthreads();

    int c = tid & 127, sl = tid >> 7;
    // v = W^T u (K-sliced over 4 groups)
    float acc = 0.f;
#pragma unroll
    for (int j = 0; j < 32; ++j) acc = fmaf(Wl[sl * 32 + j][c], us[sl * 32 + j], acc);
    part[sl][c] = acc;
    __syncthreads();
    if (tid < 128) {
        float v = part[0][tid] + part[1][tid] + part[2][tid] + part[3][tid];
        vv[tid] = v;
        red[tid] = v * v;
    }
    __syncthreads();
    for (int s = 64; s > 0; s >>= 1) { if (tid < s) red[tid] += red[tid + s]; __syncthreads(); }
    float nv = sqrtf(red[0]) + 1e-12f;
    __syncthreads();
    if (tid < 128) vv[tid] = vv[tid] / nv;
    __syncthreads();

    // t = W v
    float t = 0.f;
#pragma unroll
    for (int k = 0; k < 32; ++k) t = fmaf(Wl[c][sl * 32 + k], vv[sl * 32 + k], t);
    part[sl][c] = t;
    __syncthreads();
    if (tid < 128) {
        float tv = part[0][tid] + part[1][tid] + part[2][tid] + part[3][tid];
        red[tid] = tv * tv;
    }
    __syncthreads();
    for (int s = 64; s > 0; s >>= 1) { if (tid < s) red[tid] += red[tid + s]; __syncthreads(); }
    float tt = red[0];
    float is = (sqrtf(tt) + 1e-12f) / tt;
    if (tid == 0) inv_sigma[blockIdx.x] = is;
    if (blockIdx.x == 0) {
        // W1t[k*128+j] = W1[j][k]*is ; consecutive tid -> consecutive j -> conflict-free
        for (int idx = tid; idx < 16384; idx += 512) {
            int k = idx >> 7, j = idx & 127;
            W1t[idx] = Wl[j][k] * is;
        }
    }
}

// ---------- fused aggregation: block owns NB_AGG nodes, scans packed edges ----------
// h0[n] = x[n] + sum_{e: dst==n} x[src[e]]
__global__ __launch_bounds__(512, 1) void agg_fused_kernel(
    const float* __restrict__ x, const unsigned int* __restrict__ pk,
    float* __restrict__ h0, int n_nodes, int n_edges) {
    __shared__ float hl[NB_AGG][128];
    __shared__ unsigned int q[8][QCAP];
    int tid = threadIdx.x;
    int node0 = blockIdx.x * NB_AGG;

    // init tile with x rows (h = x + agg)
    const float4* x4 = (const float4*)x;
    for (int i = tid; i < NB_AGG * 32; i += 512) {
        int r = i >> 5, c4 = i & 31;
        int gr = node0 + r;
        float4 v = (gr < n_nodes) ? x4[(size_t)gr * 32 + c4] : make_float4(0.f, 0.f, 0.f, 0.f);
        *(float4*)&hl[r][c4 << 2] = v;
    }
    __syncthreads();

    int lane = tid & 63, w = tid >> 6;  // 8 waves
    int qc = 0;

    auto drain = [&]() {
        int j = 0;
        for (; j + 4 <= qc; j += 4) {
            uint4 e4 = *(const uint4*)&q[w][j];  // wave-uniform broadcast
            const float* r0 = &x[(size_t)(e4.x & 0xffffu) * NF];
            const float* r1 = &x[(size_t)(e4.y & 0xffffu) * NF];
            const float* r2 = &x[(size_t)(e4.z & 0xffffu) * NF];
            const float* r3 = &x[(size_t)(e4.w & 0xffffu) * NF];
            float a0 = r0[lane], b0 = r0[64 + lane];
            float a1 = r1[lane], b1 = r1[64 + lane];
            float a2 = r2[lane], b2 = r2[64 + lane];
            float a3 = r3[lane], b3 = r3[64 + lane];
            atomicAdd(&hl[e4.x >> 16][lane], a0);
            atomicAdd(&hl[e4.x >> 16][64 + lane], b0);
            atomicAdd(&hl[e4.y >> 16][lane], a1);
            atomicAdd(&hl[e4.y >> 16][64 + lane], b1);
            atomicAdd(&hl[e4.z >> 16][lane], a2);
            atomicAdd(&hl[e4.z >> 16][64 + lane], b2);
            atomicAdd(&hl[e4.w >> 16][lane], a3);
            atomicAdd(&hl[e4.w >> 16][64 + lane], b3);
        }
        for (; j < qc; ++j) {
            unsigned int pe = q[w][j];
            const float* r0 = &x[(size_t)(pe & 0xffffu) * NF];
            float a0 = r0[lane], b0 = r0[64 + lane];
            atomicAdd(&hl[pe >> 16][lane], a0);
            atomicAdd(&hl[pe >> 16][64 + lane], b0);
        }
        qc = 0;
    };

#define PROC(pe)                                                       \
    {                                                                  \
        int rel = (int)((pe) >> 16) - node0;                           \
        bool match = (unsigned)rel < (unsigned)NB_AGG;                 \
        unsigned long long m = __ballot(match);                        \
        if (match) {                                                   \
            int pos = qc + __popcll(m & ((1ULL << lane) - 1));         \
            q[w][pos] = ((unsigned)rel << 16) | ((pe) & 0xffffu);      \
        }                                                              \
        qc += (int)__popcll(m);                                        \
    }

    const uint4* pk4 = (const uint4*)pk;
    int nchunks = (n_edges + 255) >> 8;  // 256 edges per wave-chunk
    for (int ch = w; ch < nchunks; ch += 8) {
        int e0 = (ch << 8) + (lane << 2);
        uint4 u = make_uint4(0xffffffffu, 0xffffffffu, 0xffffffffu, 0xffffffffu);
        if (e0 + 3 < n_edges) {
            u = pk4[(ch << 6) + lane];
        } else {
            if (e0 < n_edges)     u.x = pk[e0];
            if (e0 + 1 < n_edges) u.y = pk[e0 + 1];
            if (e0 + 2 < n_edges) u.z = pk[e0 + 2];
        }
        PROC(u.x); PROC(u.y); PROC(u.z); PROC(u.w);
        if (qc >= QCAP - 256) drain();
    }
    drain();
#undef PROC

    __syncthreads();
    // write tile out
    for (int i = tid; i < NB_AGG * 32; i += 512) {
        int r = i >> 5, c4 = i & 31;
        int gr = node0 + r;
        if (gr < n_nodes)
            *(float4*)&h0[(size_t)gr * NF + (c4 << 2)] = *(const float4*)&hl[r][c4 << 2];
    }
}

// ---------- fallback: atomic scatter ----------
__global__ void edge_scatter_kernel(const int* __restrict__ ei, const float* __restrict__ x,
                                    float* __restrict__ h0, int n_edges) {
    int gtid = blockIdx.x * blockDim.x + threadIdx.x;
    int wid = gtid >> 6;
    int lane = threadIdx.x & 63;
    int nw = (gridDim.x * blockDim.x) >> 6;
    const int* srcs = ei;
    const int* dsts = ei + n_edges;
    for (int e = wid; e < n_edges; e += nw) {
        int s = srcs[e];
        int d = dsts[e];
        atomicAdd(&h0[d * NF + lane], x[s * NF + lane]);
        atomicAdd(&h0[d * NF + 64 + lane], x[s * NF + 64 + lane]);
    }
}

// ---------- GEMM: O = act(H @ Wt + bias); Wt is [k][c] pre-transposed ----------
// BM=32, 512 threads, thread tile 2x4. H staged in LDS (16 KB); W read from L2
// (addresses identical across blocks -> L2-hot, wave-coalesced).
template <bool RELU, bool BNACC>
__global__ __launch_bounds__(512) void gemm32_kernel(
    const float* __restrict__ H, const float* __restrict__ Wt,
    const float* __restrict__ bias, float* __restrict__ O,
    float* __restrict__ colsum, float* __restrict__ colsumsq, int n_rows) {
    __shared__ float Hl[32][128];
    int tid = threadIdx.x;
    int m0 = blockIdx.x * 32;

    const float4* H4 = (const float4*)H;
    for (int j = tid; j < 1024; j += 512) {
        int r = j >> 5, c4 = j & 31;
        int gr = m0 + r;
        float4 h = (gr < n_rows) ? H4[(size_t)gr * 32 + c4] : make_float4(0.f, 0.f, 0.f, 0.f);
        *(float4*)&Hl[r][c4 << 2] = h;
    }
    __syncthreads();

    int tx = tid & 31, ty = tid >> 5;  // ty 0..15
    int rb = ty * 2, cb = tx * 4;
    float acc[2][4] = {};
    const float4* Wt4 = (const float4*)Wt;

    for (int k = 0; k < 128; k += 4) {
        float4 w0 = Wt4[((k + 0) << 5) + tx];
        float4 w1 = Wt4[((k + 1) << 5) + tx];
        float4 w2 = Wt4[((k + 2) << 5) + tx];
        float4 w3 = Wt4[((k + 3) << 5) + tx];
#pragma unroll
        for (int i = 0; i < 2; ++i) {
            float4 h = *(const float4*)&Hl[rb + i][k];
            acc[i][0] = fmaf(h.x, w0.x, acc[i][0]);
            acc[i][0] = fmaf(h.y, w1.x, acc[i][0]);
            acc[i][0] = fmaf(h.z, w2.x, acc[i][0]);
            acc[i][0] = fmaf(h.w, w3.x, acc[i][0]);
            acc[i][1] = fmaf(h.x, w0.y, acc[i][1]);
            acc[i][1] = fmaf(h.y, w1.y, acc[i][1]);
            acc[i][1] = fmaf(h.z, w2.y, acc[i][1]);
            acc[i][1] = fmaf(h.w, w3.y, acc[i][1]);
            acc[i][2] = fmaf(h.x, w0.z, acc[i][2]);
            acc[i][2] = fmaf(h.y, w1.z, acc[i][2]);
            acc[i][2] = fmaf(h.z, w2.z, acc[i][2]);
            acc[i][2] = fmaf(h.w, w3.z, acc[i][2]);
            acc[i][3] = fmaf(h.x, w0.w, acc[i][3]);
            acc[i][3] = fmaf(h.y, w1.w, acc[i][3]);
            acc[i][3] = fmaf(h.z, w2.w, acc[i][3]);
            acc[i][3] = fmaf(h.w, w3.w, acc[i][3]);
        }
    }

    float4 bv = *(const float4*)&bias[cb];
    float bvf[4] = {bv.x, bv.y, bv.z, bv.w};
    float s[4] = {0.f, 0.f, 0.f, 0.f}, qq[4] = {0.f, 0.f, 0.f, 0.f};
#pragma unroll
    for (int i = 0; i < 2; ++i) {
        int gr = m0 + rb + i;
        if (gr < n_rows) {
            float o[4];
#pragma unroll
            for (int j = 0; j < 4; ++j) {
                float v = acc[i][j] + bvf[j];
                if (RELU) v = fmaxf(v, 0.f);
                o[j] = v;
                if (BNACC) { s[j] += v; qq[j] = fmaf(v, v, qq[j]); }
            }
            *(float4*)&O[(size_t)gr * NF + cb] = make_float4(o[0], o[1], o[2], o[3]);
        }
    }

    if (BNACC) {
        __syncthreads();  // done with Hl; reuse as reduce scratch
        float* sS = &Hl[0][0];   // rows 0..15
        float* sQ = &Hl[16][0];  // rows 16..31
#pragma unroll
        for (int j = 0; j < 4; ++j) {
            sS[ty * 128 + cb + j] = s[j];
            sQ[ty * 128 + cb + j] = qq[j];
        }
        __syncthreads();
        if (tid < 128) {
            float ts = 0.f, tq = 0.f;
#pragma unroll
            for (int g = 0; g < 16; ++g) {
                ts += sS[g * 128 + tid];
                tq += sQ[g * 128 + tid];
            }
            atomicAdd(&colsum[tid], ts);
            atomicAdd(&colsumsq[tid], tq);
        }
    }
}

// ---------- fold BN into W2', emit TRANSPOSED W2pt[k][j], b2p ----------
__global__ void fold_kernel(const float* __restrict__ W2, const float* __restrict__ b2,
                            const float* __restrict__ gamma, const float* __restrict__ beta,
                            const float* __restrict__ colsum, const float* __restrict__ colsumsq,
                            const float* __restrict__ inv_sigma, float* __restrict__ W2pt,
                            float* __restrict__ b2p, float inv_n) {
    __shared__ float a[128], cc[128], red[128];
    int k = threadIdx.x;  // 128 threads
    int j = blockIdx.x;   // 128 blocks (output row of W2)
    float mu = colsum[k] * inv_n;
    float var = colsumsq[k] * inv_n - mu * mu;
    float ai = gamma[k] / sqrtf(var + 1e-5f);
    a[k] = ai;
    cc[k] = beta[k] - ai * mu;
    __syncthreads();
    float is2 = inv_sigma[1];
    float wv = W2[j * 128 + k] * is2;
    W2pt[k * 128 + j] = wv * a[k];  // transposed store
    red[k] = wv * cc[k];
    __syncthreads();
    for (int s = 64; s > 0; s >>= 1) { if (k < s) red[k] += red[k + s]; __syncthreads(); }
    if (k == 0) b2p[j] = b2[j] + red[0];
}

extern "C" void kernel_launch(void* const* d_in, const int* in_sizes, int n_in,
                              void* d_out, int out_size, void* d_ws, size_t ws_size,
                              hipStream_t stream) {
    const float* x     = (const float*)d_in[0];
    const int*   ei    = (const int*)d_in[1];
    const float* W1    = (const float*)d_in[2];
    const float* b1    = (const float*)d_in[3];
    const float* u1    = (const float*)d_in[4];
    const float* gamma = (const float*)d_in[5];
    const float* beta  = (const float*)d_in[6];
    const float* W2    = (const float*)d_in[7];
    const float* b2    = (const float*)d_in[8];
    const float* u2    = (const float*)d_in[9];
    float* out = (float*)d_out;

    int n_nodes = in_sizes[0] / NF;
    int n_edges = in_sizes[1] / 2;

    float* ws        = (float*)d_ws;
    float* h0        = ws;                         // n_nodes*128
    float* inv_sigma = ws + (size_t)n_nodes * NF;  // 4
    float* colsum    = inv_sigma + 4;              // 128
    float* colsumsq  = colsum + 128;               // 128
    float* W1t       = colsumsq + 128;             // 128*128
    float* W2pt      = W1t + 128 * 128;            // 128*128
    float* b2p       = W2pt + 128 * 128;           // 128
    unsigned int* pk = (unsigned int*)(b2p + 128); // n_edges

    size_t need = ((size_t)n_nodes * NF + 4 + 256 + 2 * 128 * 128 + 128) * sizeof(float)
                + (size_t)n_edges * sizeof(unsigned int);
    bool fused = (n_nodes <= 65000) && (ws_size >= need);

    if (fused) {
        // power iteration + W1t + colsum zero + edge packing, one kernel
        power_pack_kernel<<<130, 512, 0, stream>>>(W1, u1, W2, u2, ei, pk, n_edges,
                                                   inv_sigma, W1t, colsum);
        int nblk = (n_nodes + NB_AGG - 1) / NB_AGG;
        agg_fused_kernel<<<nblk, 512, 0, stream>>>(x, pk, h0, n_nodes, n_edges);
    } else {
        power_pack_kernel<<<2, 512, 0, stream>>>(W1, u1, W2, u2, ei, pk, n_edges,
                                                 inv_sigma, W1t, colsum);
        hipMemcpyAsync(h0, x, (size_t)n_nodes * NF * sizeof(float),
                       hipMemcpyDeviceToDevice, stream);
        edge_scatter_kernel<<<2048, 256, 0, stream>>>(ei, x, h0, n_edges);
    }

    int gemm_blocks = (n_nodes + 31) / 32;

    // h1 = relu(h0 @ W1sn^T + b1) -> d_out, fused BN col stats
    gemm32_kernel<true, true><<<gemm_blocks, 512, 0, stream>>>(
        h0, W1t, b1, out, colsum, colsumsq, n_nodes);

    fold_kernel<<<128, 128, 0, stream>>>(W2, b2, gamma, beta, colsum, colsumsq,
                                         inv_sigma, W2pt, b2p, 1.0f / (float)n_nodes);

    // out = h1 @ W2p^T + b2p  (in-place: block stages its own rows first)
    gemm32_kernel<false, false><<<gemm_blocks, 512, 0, stream>>>(
        out, W2pt, b2p, out, nullptr, nullptr, n_nodes);
}

// Round 5
// 830.717 us; speedup vs baseline: 1.1160x; 1.1160x over previous
//
#include <hip/hip_runtime.h>

#define NF 128
#define BIN_SHIFT 4
#define BIN_NODES 16
#define FB 128          // hist/fill partition blocks
#define MAXBIN 2560     // LDS cursor capacity -> n_nodes <= 40960 for fused path

// ---------- power iteration (blocks 0,1) + per-chunk edge histogram (blocks >=2) ----------
// block 0: inv_sigma[0], W1t[k][j] = W1[j][k]*inv_sigma[0], zero colsum/colsumsq
// block 1: inv_sigma[1]
// block 2+fb: hist2d[fb][bin] = count of edges in chunk fb with dst>>4 == bin
__global__ __launch_bounds__(512) void power_hist_kernel(
    const float* __restrict__ W1, const float* __restrict__ u1,
    const float* __restrict__ W2, const float* __restrict__ u2,
    const int* __restrict__ dst, int n_edges,
    int* __restrict__ hist2d, int nbin,
    float* __restrict__ inv_sigma, float* __restrict__ W1t,
    float* __restrict__ colzero) {
    __shared__ float Wl[128][129];
    __shared__ float us[128], vv[128], part[4][128], red[128];
    __shared__ int hist[MAXBIN];
    int tid = threadIdx.x;

    if (blockIdx.x >= 2) {
        int fb = blockIdx.x - 2;
        for (int i = tid; i < nbin; i += 512) hist[i] = 0;
        __syncthreads();
        int chunk = (n_edges + FB - 1) / FB;
        int e0 = fb * chunk, e1 = min(e0 + chunk, n_edges);
        for (int e = e0 + tid; e < e1; e += 512)
            atomicAdd(&hist[dst[e] >> BIN_SHIFT], 1);
        __syncthreads();
        for (int i = tid; i < nbin; i += 512) hist2d[fb * nbin + i] = hist[i];
        return;
    }

    const float* W = blockIdx.x ? W2 : W1;
    const float* u = blockIdx.x ? u2 : u1;
    const float4* W4 = (const float4*)W;
    for (int j = tid; j < 4096; j += 512) {
        float4 w = W4[j];
        int r = j >> 5, c0 = (j & 31) << 2;
        Wl[r][c0] = w.x; Wl[r][c0 + 1] = w.y; Wl[r][c0 + 2] = w.z; Wl[r][c0 + 3] = w.w;
    }
    if (tid < 128) us[tid] = u[tid];
    if (blockIdx.x == 0 && tid >= 256 && tid < 512) colzero[tid - 256] = 0.f;
    __syncthreads();

    int c = tid & 127, sl = tid >> 7;
    // v = W^T u (K-sliced over 4 groups)
    float acc = 0.f;
#pragma unroll
    for (int j = 0; j < 32; ++j) acc = fmaf(Wl[sl * 32 + j][c], us[sl * 32 + j], acc);
    part[sl][c] = acc;
    __syncthreads();
    if (tid < 128) {
        float v = part[0][tid] + part[1][tid] + part[2][tid] + part[3][tid];
        vv[tid] = v;
        red[tid] = v * v;
    }
    __syncthreads();
    for (int s = 64; s > 0; s >>= 1) { if (tid < s) red[tid] += red[tid + s]; __syncthreads(); }
    float nv = sqrtf(red[0]) + 1e-12f;
    __syncthreads();
    if (tid < 128) vv[tid] = vv[tid] / nv;
    __syncthreads();

    // t = W v
    float t = 0.f;
#pragma unroll
    for (int k = 0; k < 32; ++k) t = fmaf(Wl[c][sl * 32 + k], vv[sl * 32 + k], t);
    part[sl][c] = t;
    __syncthreads();
    if (tid < 128) {
        float tv = part[0][tid] + part[1][tid] + part[2][tid] + part[3][tid];
        red[tid] = tv * tv;
    }
    __syncthreads();
    for (int s = 64; s > 0; s >>= 1) { if (tid < s) red[tid] += red[tid + s]; __syncthreads(); }
    float tt = red[0];
    float is = (sqrtf(tt) + 1e-12f) / tt;
    if (tid == 0) inv_sigma[blockIdx.x] = is;
    if (blockIdx.x == 0) {
        for (int idx = tid; idx < 16384; idx += 512) {
            int k = idx >> 7, j = idx & 127;
            W1t[idx] = Wl[j][k] * is;  // consecutive tid -> consecutive j -> conflict-free
        }
    }
}

// ---------- scan: hist2d -> per-(fb,bin) exclusive prefix over fb; binOff = bin bases ------
__global__ void scan2d_kernel(int* __restrict__ hist2d, int* __restrict__ binOff, int nbin) {
    __shared__ int sc[1024];
    int tid = threadIdx.x;
    int C = (nbin + 1023) >> 10;
    int b0 = tid * C, b1 = min(b0 + C, nbin);
    int tot = 0;
    for (int bin = b0; bin < b1; ++bin) {
        binOff[bin] = tot;  // thread-local exclusive prefix (temp)
        int run = 0;
        for (int fb = 0; fb < FB; ++fb) {
            int v = hist2d[fb * nbin + bin];
            hist2d[fb * nbin + bin] = run;  // exclusive prefix within bin over fb
            run += v;
        }
        tot += run;
    }
    sc[tid] = tot;
    __syncthreads();
    for (int off = 1; off < 1024; off <<= 1) {
        int v = (tid >= off) ? sc[tid - off] : 0;
        __syncthreads();
        sc[tid] += v;
        __syncthreads();
    }
    int excl = sc[tid] - tot;
    for (int bin = b0; bin < b1; ++bin) binOff[bin] += excl;
    if (tid == 1023) binOff[nbin] = sc[1023];
}

// ---------- fill: place edges into bins via LDS cursors (deterministic block bases) --------
__global__ __launch_bounds__(512) void fill_kernel(
    const int* __restrict__ src, const int* __restrict__ dst,
    const int* __restrict__ hist2d, const int* __restrict__ binOff,
    unsigned int* __restrict__ bucket, int nbin, int n_edges) {
    __shared__ int cur[MAXBIN];
    int tid = threadIdx.x;
    int fb = blockIdx.x;
    for (int i = tid; i < nbin; i += 512) cur[i] = hist2d[fb * nbin + i] + binOff[i];
    __syncthreads();
    int chunk = (n_edges + FB - 1) / FB;
    int e0 = fb * chunk, e1 = min(e0 + chunk, n_edges);
    for (int e = e0 + tid; e < e1; e += 512) {
        int d = dst[e];
        int s = src[e];
        int pos = atomicAdd(&cur[d >> BIN_SHIFT], 1);
        bucket[pos] = ((unsigned)(d & (BIN_NODES - 1)) << 16) | (unsigned)s;
    }
}

// ---------- fused: aggregate 16-node LDS tile from own bucket slice, then GEMM1 ------------
// hl = x[tile] + sum x[src]; out = relu(hl @ W1t + b1); BN col stats accumulated
__global__ __launch_bounds__(256) void agg_gemm1_kernel(
    const float* __restrict__ x, const unsigned int* __restrict__ bucket,
    const int* __restrict__ binOff, const float* __restrict__ Wt,
    const float* __restrict__ bias, float* __restrict__ O,
    float* __restrict__ colsum, float* __restrict__ colsumsq, int n_nodes) {
    __shared__ float hl[BIN_NODES][132];  // +4 pad: rows 16B-aligned, 2-way bank alias only
    int tid = threadIdx.x;
    int node0 = blockIdx.x * BIN_NODES;

    // init tile = x rows (h = x + agg)
    const float4* x4 = (const float4*)x;
    for (int i = tid; i < BIN_NODES * 32; i += 256) {
        int r = i >> 5, c4 = i & 31;
        int gr = node0 + r;
        float4 v = (gr < n_nodes) ? x4[(size_t)gr * 32 + c4] : make_float4(0.f, 0.f, 0.f, 0.f);
        *(float4*)&hl[r][c4 << 2] = v;
    }
    __syncthreads();

    int lane = tid & 63, w = tid >> 6;  // 4 waves
    int start = binOff[blockIdx.x], end = binOff[blockIdx.x + 1];
    for (int j = start + w * 4; j < end; j += 16) {
        int m = end - j;  // >=1
        float av[4], bv_[4];
        int rel[4];
#pragma unroll
        for (int t = 0; t < 4; ++t) {
            if (t < m) {
                unsigned pe = bucket[j + t];  // wave-uniform broadcast
                rel[t] = (int)(pe >> 16);
                const float* row = &x[(size_t)(pe & 0xffffu) * NF];
                av[t] = row[lane];
                bv_[t] = row[64 + lane];
            }
        }
#pragma unroll
        for (int t = 0; t < 4; ++t) {
            if (t < m) {
                atomicAdd(&hl[rel[t]][lane], av[t]);        // ds_add_f32, no return
                atomicAdd(&hl[rel[t]][64 + lane], bv_[t]);
            }
        }
    }
    __syncthreads();

    // GEMM: O[tile] = relu(hl @ Wt + bias); Wt [k][c] from L2 (same addrs across blocks)
    int tx = tid & 31, ty = tid >> 5;  // ty 0..7
    int rb = ty * 2, cb = tx * 4;
    float acc[2][4] = {};
    const float4* Wt4 = (const float4*)Wt;
    for (int k = 0; k < 128; k += 4) {
        float4 w0 = Wt4[((k + 0) << 5) + tx];
        float4 w1 = Wt4[((k + 1) << 5) + tx];
        float4 w2 = Wt4[((k + 2) << 5) + tx];
        float4 w3 = Wt4[((k + 3) << 5) + tx];
#pragma unroll
        for (int i = 0; i < 2; ++i) {
            float4 h = *(const float4*)&hl[rb + i][k];
            acc[i][0] = fmaf(h.x, w0.x, acc[i][0]);
            acc[i][0] = fmaf(h.y, w1.x, acc[i][0]);
            acc[i][0] = fmaf(h.z, w2.x, acc[i][0]);
            acc[i][0] = fmaf(h.w, w3.x, acc[i][0]);
            acc[i][1] = fmaf(h.x, w0.y, acc[i][1]);
            acc[i][1] = fmaf(h.y, w1.y, acc[i][1]);
            acc[i][1] = fmaf(h.z, w2.y, acc[i][1]);
            acc[i][1] = fmaf(h.w, w3.y, acc[i][1]);
            acc[i][2] = fmaf(h.x, w0.z, acc[i][2]);
            acc[i][2] = fmaf(h.y, w1.z, acc[i][2]);
            acc[i][2] = fmaf(h.z, w2.z, acc[i][2]);
            acc[i][2] = fmaf(h.w, w3.z, acc[i][2]);
            acc[i][3] = fmaf(h.x, w0.w, acc[i][3]);
            acc[i][3] = fmaf(h.y, w1.w, acc[i][3]);
            acc[i][3] = fmaf(h.z, w2.w, acc[i][3]);
            acc[i][3] = fmaf(h.w, w3.w, acc[i][3]);
        }
    }

    float4 bv = *(const float4*)&bias[cb];
    float bvf[4] = {bv.x, bv.y, bv.z, bv.w};
    float s[4] = {0.f, 0.f, 0.f, 0.f}, qq[4] = {0.f, 0.f, 0.f, 0.f};
#pragma unroll
    for (int i = 0; i < 2; ++i) {
        int gr = node0 + rb + i;
        if (gr < n_nodes) {
            float o[4];
#pragma unroll
            for (int j = 0; j < 4; ++j) {
                float v = acc[i][j] + bvf[j];
                v = fmaxf(v, 0.f);
                o[j] = v;
                s[j] += v;
                qq[j] = fmaf(v, v, qq[j]);
            }
            *(float4*)&O[(size_t)gr * NF + cb] = make_float4(o[0], o[1], o[2], o[3]);
        }
    }

    __syncthreads();  // done with hl; reuse as BN reduce scratch (needs 2048 <= 2112 floats)
    float* sS = &hl[0][0];
    float* sQ = &hl[0][0] + 1024;
#pragma unroll
    for (int j = 0; j < 4; ++j) {
        sS[ty * 128 + cb + j] = s[j];
        sQ[ty * 128 + cb + j] = qq[j];
    }
    __syncthreads();
    if (tid < 128) {
        float ts = 0.f, tq = 0.f;
#pragma unroll
        for (int g = 0; g < 8; ++g) {
            ts += sS[g * 128 + tid];
            tq += sQ[g * 128 + tid];
        }
        atomicAdd(&colsum[tid], ts);
        atomicAdd(&colsumsq[tid], tq);
    }
}

// ---------- fallback: atomic scatter ----------
__global__ void edge_scatter_kernel(const int* __restrict__ ei, const float* __restrict__ x,
                                    float* __restrict__ h0, int n_edges) {
    int gtid = blockIdx.x * blockDim.x + threadIdx.x;
    int wid = gtid >> 6;
    int lane = threadIdx.x & 63;
    int nw = (gridDim.x * blockDim.x) >> 6;
    const int* srcs = ei;
    const int* dsts = ei + n_edges;
    for (int e = wid; e < n_edges; e += nw) {
        int s = srcs[e];
        int d = dsts[e];
        atomicAdd(&h0[d * NF + lane], x[s * NF + lane]);
        atomicAdd(&h0[d * NF + 64 + lane], x[s * NF + 64 + lane]);
    }
}

// ---------- GEMM: O = act(H @ Wt + bias); Wt [k][c] pre-transposed; BM=32, 512 thr --------
template <bool RELU, bool BNACC>
__global__ __launch_bounds__(512) void gemm32_kernel(
    const float* __restrict__ H, const float* __restrict__ Wt,
    const float* __restrict__ bias, float* __restrict__ O,
    float* __restrict__ colsum, float* __restrict__ colsumsq, int n_rows) {
    __shared__ float Hl[32][128];
    int tid = threadIdx.x;
    int m0 = blockIdx.x * 32;

    const float4* H4 = (const float4*)H;
    for (int j = tid; j < 1024; j += 512) {
        int r = j >> 5, c4 = j & 31;
        int gr = m0 + r;
        float4 h = (gr < n_rows) ? H4[(size_t)gr * 32 + c4] : make_float4(0.f, 0.f, 0.f, 0.f);
        *(float4*)&Hl[r][c4 << 2] = h;
    }
    __syncthreads();

    int tx = tid & 31, ty = tid >> 5;  // ty 0..15
    int rb = ty * 2, cb = tx * 4;
    float acc[2][4] = {};
    const float4* Wt4 = (const float4*)Wt;

    for (int k = 0; k < 128; k += 4) {
        float4 w0 = Wt4[((k + 0) << 5) + tx];
        float4 w1 = Wt4[((k + 1) << 5) + tx];
        float4 w2 = Wt4[((k + 2) << 5) + tx];
        float4 w3 = Wt4[((k + 3) << 5) + tx];
#pragma unroll
        for (int i = 0; i < 2; ++i) {
            float4 h = *(const float4*)&Hl[rb + i][k];
            acc[i][0] = fmaf(h.x, w0.x, acc[i][0]);
            acc[i][0] = fmaf(h.y, w1.x, acc[i][0]);
            acc[i][0] = fmaf(h.z, w2.x, acc[i][0]);
            acc[i][0] = fmaf(h.w, w3.x, acc[i][0]);
            acc[i][1] = fmaf(h.x, w0.y, acc[i][1]);
            acc[i][1] = fmaf(h.y, w1.y, acc[i][1]);
            acc[i][1] = fmaf(h.z, w2.y, acc[i][1]);
            acc[i][1] = fmaf(h.w, w3.y, acc[i][1]);
            acc[i][2] = fmaf(h.x, w0.z, acc[i][2]);
            acc[i][2] = fmaf(h.y, w1.z, acc[i][2]);
            acc[i][2] = fmaf(h.z, w2.z, acc[i][2]);
            acc[i][2] = fmaf(h.w, w3.z, acc[i][2]);
            acc[i][3] = fmaf(h.x, w0.w, acc[i][3]);
            acc[i][3] = fmaf(h.y, w1.w, acc[i][3]);
            acc[i][3] = fmaf(h.z, w2.w, acc[i][3]);
            acc[i][3] = fmaf(h.w, w3.w, acc[i][3]);
        }
    }

    float4 bv = *(const float4*)&bias[cb];
    float bvf[4] = {bv.x, bv.y, bv.z, bv.w};
    float s[4] = {0.f, 0.f, 0.f, 0.f}, qq[4] = {0.f, 0.f, 0.f, 0.f};
#pragma unroll
    for (int i = 0; i < 2; ++i) {
        int gr = m0 + rb + i;
        if (gr < n_rows) {
            float o[4];
#pragma unroll
            for (int j = 0; j < 4; ++j) {
                float v = acc[i][j] + bvf[j];
                if (RELU) v = fmaxf(v, 0.f);
                o[j] = v;
                if (BNACC) { s[j] += v; qq[j] = fmaf(v, v, qq[j]); }
            }
            *(float4*)&O[(size_t)gr * NF + cb] = make_float4(o[0], o[1], o[2], o[3]);
        }
    }

    if (BNACC) {
        __syncthreads();
        float* sS = &Hl[0][0];
        float* sQ = &Hl[16][0];
#pragma unroll
        for (int j = 0; j < 4; ++j) {
            sS[ty * 128 + cb + j] = s[j];
            sQ[ty * 128 + cb + j] = qq[j];
        }
        __syncthreads();
        if (tid < 128) {
            float ts = 0.f, tq = 0.f;
#pragma unroll
            for (int g = 0; g < 16; ++g) {
                ts += sS[g * 128 + tid];
                tq += sQ[g * 128 + tid];
            }
            atomicAdd(&colsum[tid], ts);
            atomicAdd(&colsumsq[tid], tq);
        }
    }
}

// ---------- fold BN into W2', emit TRANSPOSED W2pt[k][j], b2p ----------
__global__ void fold_kernel(const float* __restrict__ W2, const float* __restrict__ b2,
                            const float* __restrict__ gamma, const float* __restrict__ beta,
                            const float* __restrict__ colsum, const float* __restrict__ colsumsq,
                            const float* __restrict__ inv_sigma, float* __restrict__ W2pt,
                            float* __restrict__ b2p, float inv_n) {
    __shared__ float a[128], cc[128], red[128];
    int k = threadIdx.x;  // 128 threads
    int j = blockIdx.x;   // 128 blocks (output row of W2)
    float mu = colsum[k] * inv_n;
    float var = colsumsq[k] * inv_n - mu * mu;
    float ai = gamma[k] / sqrtf(var + 1e-5f);
    a[k] = ai;
    cc[k] = beta[k] - ai * mu;
    __syncthreads();
    float is2 = inv_sigma[1];
    float wv = W2[j * 128 + k] * is2;
    W2pt[k * 128 + j] = wv * a[k];  // transposed store
    red[k] = wv * cc[k];
    __syncthreads();
    for (int s = 64; s > 0; s >>= 1) { if (k < s) red[k] += red[k + s]; __syncthreads(); }
    if (k == 0) b2p[j] = b2[j] + red[0];
}

extern "C" void kernel_launch(void* const* d_in, const int* in_sizes, int n_in,
                              void* d_out, int out_size, void* d_ws, size_t ws_size,
                              hipStream_t stream) {
    const float* x     = (const float*)d_in[0];
    const int*   ei    = (const int*)d_in[1];
    const float* W1    = (const float*)d_in[2];
    const float* b1    = (const float*)d_in[3];
    const float* u1    = (const float*)d_in[4];
    const float* gamma = (const float*)d_in[5];
    const float* beta  = (const float*)d_in[6];
    const float* W2    = (const float*)d_in[7];
    const float* b2    = (const float*)d_in[8];
    const float* u2    = (const float*)d_in[9];
    float* out = (float*)d_out;

    int n_nodes = in_sizes[0] / NF;
    int n_edges = in_sizes[1] / 2;
    int nbin = (n_nodes + BIN_NODES - 1) / BIN_NODES;

    float* ws        = (float*)d_ws;
    float* inv_sigma = ws;                // 4
    float* colsum    = ws + 4;            // 128
    float* colsumsq  = colsum + 128;      // 128
    float* W1t       = colsumsq + 128;    // 16384
    float* W2pt      = W1t + 16384;       // 16384
    float* b2p       = W2pt + 16384;      // 128
    // union region:
    int*   binOff    = (int*)(b2p + 128);            // nbin+1
    int*   hist2d    = binOff + nbin + 1;            // FB*nbin
    unsigned int* bucket = (unsigned int*)(hist2d + (size_t)FB * nbin);  // n_edges
    float* h0        = (float*)(b2p + 128);          // fallback: n_nodes*128

    size_t fixed = (4 + 256 + 2 * 16384 + 128) * sizeof(float);
    size_t fused_need = fixed + ((size_t)nbin + 1 + (size_t)FB * nbin + n_edges) * sizeof(int);
    size_t fb_need    = fixed + (size_t)n_nodes * NF * sizeof(float);
    bool fused = (nbin <= MAXBIN) && (n_nodes <= 65536) && (ws_size >= fused_need);

    if (fused) {
        // power iter + W1t + colsum zero (blocks 0,1); edge hist (blocks 2..FB+1)
        power_hist_kernel<<<FB + 2, 512, 0, stream>>>(W1, u1, W2, u2, ei + n_edges, n_edges,
                                                      hist2d, nbin, inv_sigma, W1t, colsum);
        scan2d_kernel<<<1, 1024, 0, stream>>>(hist2d, binOff, nbin);
        fill_kernel<<<FB, 512, 0, stream>>>(ei, ei + n_edges, hist2d, binOff, bucket,
                                            nbin, n_edges);
        // agg into LDS tiles + GEMM1 + ReLU + BN stats -> d_out
        agg_gemm1_kernel<<<nbin, 256, 0, stream>>>(x, bucket, binOff, W1t, b1, out,
                                                   colsum, colsumsq, n_nodes);
    } else {
        power_hist_kernel<<<2, 512, 0, stream>>>(W1, u1, W2, u2, ei + n_edges, n_edges,
                                                 nullptr, nbin, inv_sigma, W1t, colsum);
        hipMemcpyAsync(h0, x, (size_t)n_nodes * NF * sizeof(float),
                       hipMemcpyDeviceToDevice, stream);
        if (ws_size >= fb_need)
            edge_scatter_kernel<<<2048, 256, 0, stream>>>(ei, x, h0, n_edges);
        gemm32_kernel<true, true><<<(n_nodes + 31) / 32, 512, 0, stream>>>(
            h0, W1t, b1, out, colsum, colsumsq, n_nodes);
    }

    fold_kernel<<<128, 128, 0, stream>>>(W2, b2, gamma, beta, colsum, colsumsq,
                                         inv_sigma, W2pt, b2p, 1.0f / (float)n_nodes);

    // out = h1 @ W2p^T + b2p  (in-place: block stages its own rows first)
    gemm32_kernel<false, false><<<(n_nodes + 31) / 32, 512, 0, stream>>>(
        out, W2pt, b2p, out, nullptr, nullptr, n_nodes);
}